// Round 1
// baseline (97.333 us; speedup 1.0000x reference)
//
#include <hip/hip_runtime.h>
#include <math.h>

#define OUT_H 7
#define OUT_W 7
#define N_C 256
#define FH 38
#define FW 38
#define NUM_ROIS 256
#define SPATIAL_SCALE 0.0625f

// Channels per block; 8 -> LDS rowmax = 8*7*38*4 = 8512 B, grid = 256 rois * 32
// chunks = 8192 blocks (32 blocks/CU).
#define CC 8
#define CHUNKS (N_C / CC)

// Two-phase ROI max pool, one block per (roi, 8-channel chunk).
//
// Phase A (separable row reduction): rowmax[c][i][w] = max over the i-th h-bin
// of feat[b][c][h][w], for ALL w in [0,38). Task id is w-fastest, so the 64
// lanes of a wave read contiguous w -> fully coalesced 152 B row segments, and
// the h trip count is uniform across each 38-lane w-group (no worst-lane
// serialization like the old per-output-element kernel).
//
// Phase B: out[i][j] = max over w-bin j of rowmax[c][i][w], read from LDS.
// Writes are lane-consecutive -> coalesced.
//
// ROI bounds depend only on (r,i,j); they are computed once per block (scalar,
// via readfirstlane) instead of once per channel like before.
__global__ __launch_bounds__(256) void roi_pool_kernel(
    const float* __restrict__ feat,
    const float* __restrict__ rois,
    float* __restrict__ out)
{
    __shared__ float rowmax[CC][OUT_H][FW];

    int blk   = blockIdx.x;
    int r     = blk / CHUNKS;
    int chunk = blk - r * CHUNKS;
    int c0    = chunk * CC;

    // All lanes load the same 5 floats (L1 broadcast); force the decoded
    // bounds into SGPRs so the loop bounds/addressing are scalar.
    const float* roi = rois + r * 5;
    int b  = __builtin_amdgcn_readfirstlane((int)roi[0]);
    int x1 = __builtin_amdgcn_readfirstlane((int)(roi[1] * SPATIAL_SCALE));
    int y1 = __builtin_amdgcn_readfirstlane((int)(roi[2] * SPATIAL_SCALE));
    int x2 = __builtin_amdgcn_readfirstlane((int)(roi[3] * SPATIAL_SCALE));
    int y2 = __builtin_amdgcn_readfirstlane((int)(roi[4] * SPATIAL_SCALE));
    int rh = y2 - y1 + 1;  // >= 1
    int rw = x2 - x1 + 1;  // >= 1

    int tid = threadIdx.x;

    // ---- Phase A: row maxima over h-bins, all 38 columns ----
    const int TA = CC * OUT_H * FW;  // 2128 tasks
    const float* fbase = feat + ((size_t)b * N_C + c0) * (FH * FW);
    for (int task = tid; task < TA; task += 256) {
        int w  = task % FW;          // fastest -> coalesced
        int iw = task / FW;          // cl*7 + i
        int i  = iw % OUT_H;
        int cl = iw / OUT_H;
        // Python floor-div on non-negative ints == C int div
        int hstart = y1 + (i * rh) / OUT_H;
        int hend   = y1 + ((i + 1) * rh + OUT_H - 1) / OUT_H;  // > hstart
        const float* fp = fbase + cl * (FH * FW) + w;
        float m = -INFINITY;
        for (int h = hstart; h < hend; ++h)
            m = fmaxf(m, fp[h * FW]);
        rowmax[cl][i][w] = m;
    }
    __syncthreads();

    // ---- Phase B: column reduction from LDS, coalesced stores ----
    const int TB = CC * OUT_H * OUT_W;  // 392 tasks
    float* obase = out + ((size_t)r * N_C + c0) * (OUT_H * OUT_W);
    for (int task = tid; task < TB; task += 256) {
        int pos = task % (OUT_H * OUT_W);
        int cl  = task / (OUT_H * OUT_W);
        int i   = pos / OUT_W;
        int j   = pos - i * OUT_W;
        int wstart = x1 + (j * rw) / OUT_W;
        int wend   = x1 + ((j + 1) * rw + OUT_W - 1) / OUT_W;  // > wstart
        float m = -INFINITY;
        for (int w = wstart; w < wend; ++w)
            m = fmaxf(m, rowmax[cl][i][w]);
        obase[task] = m;
    }
}

extern "C" void kernel_launch(void* const* d_in, const int* in_sizes, int n_in,
                              void* d_out, int out_size, void* d_ws, size_t ws_size,
                              hipStream_t stream) {
    const float* feat = (const float*)d_in[0];
    const float* rois = (const float*)d_in[1];
    float* out = (float*)d_out;

    int grid  = NUM_ROIS * CHUNKS;  // 8192
    int block = 256;
    roi_pool_kernel<<<grid, block, 0, stream>>>(feat, rois, out);
}

// Round 3
// 77.912 us; speedup vs baseline: 1.2493x; 1.2493x over previous
//
#include <hip/hip_runtime.h>
#include <math.h>

#define OUT_H 7
#define OUT_W 7
#define N_C 256
#define FH 38
#define FW 38
#define NUM_ROIS 256
#define SPATIAL_SCALE 0.0625f
#define PLANE (FH * FW)

// Channels per block; 8 -> LDS rowmax = 8*7*38*4 = 8512 B.
#define CC 8
#define CHUNKS (N_C / CC)

// Two-phase separable ROI max pool, one block per (roi, 8-channel chunk).
//
// Index map is STRUCTURAL: blockDim=(38,7) so w=threadIdx.x, i=threadIdx.y.
// No div/mod decode in Phase A (round-1 post-mortem: grid-stride decode was
// ~150 VALU instrs per ~2-fmax task -> VALU-bound at 47 us). The channel loop
// is a compile-time unrolled register dimension: 8 independent cached loads
// per h-step -> ILP hides L1/L2 latency.
//
// Bounds safety (container-crash audit): y2 <= floor(607.9/16) = 37, so
// hend <= 38 = FH; likewise wend <= 38 = FW; b in {0,1}. The single
// __syncthreads() is reached unconditionally by all threads.
__global__ __launch_bounds__(266) void roi_pool_kernel(
    const float* __restrict__ feat,
    const float* __restrict__ rois,
    float* __restrict__ out)
{
    __shared__ float rowmax[CC][OUT_H][FW];

    int blk   = blockIdx.x;
    int r     = blk / CHUNKS;
    int chunk = blk - r * CHUNKS;
    int c0    = chunk * CC;

    // All lanes read the same 5 floats (L1 broadcast); bounds forced scalar.
    const float* roi = rois + r * 5;
    int b  = __builtin_amdgcn_readfirstlane((int)roi[0]);
    int x1 = __builtin_amdgcn_readfirstlane((int)(roi[1] * SPATIAL_SCALE));
    int y1 = __builtin_amdgcn_readfirstlane((int)(roi[2] * SPATIAL_SCALE));
    int x2 = __builtin_amdgcn_readfirstlane((int)(roi[3] * SPATIAL_SCALE));
    int y2 = __builtin_amdgcn_readfirstlane((int)(roi[4] * SPATIAL_SCALE));
    int rh = y2 - y1 + 1;  // >= 1
    int rw = x2 - x1 + 1;  // >= 1

    int w = threadIdx.x;   // 0..37  (lane-contiguous -> coalesced loads)
    int i = threadIdx.y;   // 0..6   (output row bin)

    // Python floor-div on non-negative ints == C int div; computed ONCE.
    int hstart = y1 + (i * rh) / OUT_H;
    int hend   = y1 + ((i + 1) * rh + OUT_H - 1) / OUT_H;  // > hstart always

    // Scalar base (b,c0 uniform) + vector column offset w.
    const float* fcol = feat + ((size_t)b * N_C + c0) * PLANE + w;

    float m[CC];
    #pragma unroll
    for (int cl = 0; cl < CC; ++cl) m[cl] = -INFINITY;

    for (int h = hstart; h < hend; ++h) {
        int off = h * FW;
        #pragma unroll
        for (int cl = 0; cl < CC; ++cl)
            m[cl] = fmaxf(m[cl], fcol[off + cl * PLANE]);
    }

    #pragma unroll
    for (int cl = 0; cl < CC; ++cl)
        rowmax[cl][i][w] = m[cl];   // lane-consecutive ds_write, conflict-free

    __syncthreads();

    // ---- Phase B: column reduction from LDS, coalesced stores ----
    // Only 392 tasks / 266 threads; one-time decode cost is negligible.
    int t = threadIdx.y * FW + threadIdx.x;  // 0..265 linear
    float* obase = out + ((size_t)r * N_C + c0) * (OUT_H * OUT_W);
    for (int task = t; task < CC * OUT_H * OUT_W; task += 266) {
        int cl  = task / (OUT_H * OUT_W);
        int pos = task - cl * (OUT_H * OUT_W);
        int oi  = pos / OUT_W;
        int j   = pos - oi * OUT_W;
        int wstart = x1 + (j * rw) / OUT_W;
        int wend   = x1 + ((j + 1) * rw + OUT_W - 1) / OUT_W;  // > wstart
        float mm = -INFINITY;
        for (int ww = wstart; ww < wend; ++ww)
            mm = fmaxf(mm, rowmax[cl][oi][ww]);
        obase[task] = mm;  // consecutive addresses across the wave
    }
}

extern "C" void kernel_launch(void* const* d_in, const int* in_sizes, int n_in,
                              void* d_out, int out_size, void* d_ws, size_t ws_size,
                              hipStream_t stream) {
    const float* feat = (const float*)d_in[0];
    const float* rois = (const float*)d_in[1];
    float* out = (float*)d_out;

    dim3 block(FW, OUT_H);           // 38 x 7 = 266 threads (5 waves)
    int  grid = NUM_ROIS * CHUNKS;   // 8192 blocks
    roi_pool_kernel<<<grid, block, 0, stream>>>(feat, rois, out);
}

// Round 4
// 77.906 us; speedup vs baseline: 1.2494x; 1.0001x over previous
//
#include <hip/hip_runtime.h>
#include <math.h>

#define OUT_H 7
#define OUT_W 7
#define N_C 256
#define FH 38
#define FW 38
#define NUM_ROIS 256
#define SPATIAL_SCALE 0.0625f
#define PLANE (FH * FW)

// Channels per block: 16 -> LDS rowmax = 16*7*38*4 = 17024 B, grid = 4096.
#define CC 16
#define CHUNKS (N_C / CC)

// v4: separable two-phase ROI max pool, one block per (roi, 16-channel chunk).
// Round-3 post-mortem: kernel ~28us, VMEM-instruction/TA-bound (900K wave-loads
// of scalar dwords, 38/64 lanes useful). Fixes here:
//  - float2 (dwordx2) feature loads: rows are 152 B and all offsets 8B-aligned
//    (PLANE*4=5776, FW*4=152 both %8==0) -> half the load instructions.
//  - CC=16: half the blocks -> half the per-block roi-load/decode latency cost.
//  - channel base pointers derive only from readfirstlane'd scalars -> compiler
//    emits saddr-form global_load (scalar base + 32b voffset): 1 VALU add per
//    h-step instead of 16.
//  - Phase B: w-bounds computed once into LDS; one (i,j) decode amortized over
//    4 channels; coalesced 49-float store segments.
// Bounds safety: y2,x2 <= floor(607.9*0.0625)=37 -> hend,wend <= 38; b in {0,1}.
// The single __syncthreads() is reached unconditionally.
__global__ __launch_bounds__(266) void roi_pool_kernel(
    const float* __restrict__ feat,
    const float* __restrict__ rois,
    float* __restrict__ out)
{
    __shared__ float rowmax[CC][OUT_H][FW];
    __shared__ int wse[2][OUT_W];

    int blk   = blockIdx.x;
    int r     = blk / CHUNKS;
    int chunk = blk - r * CHUNKS;
    int c0    = chunk * CC;

    // All lanes read the same 5 floats (L1 broadcast); bounds forced scalar.
    const float* roi = rois + r * 5;
    int b  = __builtin_amdgcn_readfirstlane((int)roi[0]);
    int x1 = __builtin_amdgcn_readfirstlane((int)(roi[1] * SPATIAL_SCALE));
    int y1 = __builtin_amdgcn_readfirstlane((int)(roi[2] * SPATIAL_SCALE));
    int x2 = __builtin_amdgcn_readfirstlane((int)(roi[3] * SPATIAL_SCALE));
    int y2 = __builtin_amdgcn_readfirstlane((int)(roi[4] * SPATIAL_SCALE));
    int rh = y2 - y1 + 1;  // >= 1
    int rw = x2 - x1 + 1;  // >= 1

    int tx = threadIdx.x;  // 0..18 : float2 column (w = 2*tx, 2*tx+1)
    int ty = threadIdx.y;  // 0..6  : output row bin i
    int tz = threadIdx.z;  // 0..1  : which 8-channel half
    int lin = tx + 19 * (ty + 7 * tz);  // 0..265

    // w-bin bounds once per block (7 threads), consumed by Phase B after the
    // barrier. Python floor-div on non-negative ints == C int div.
    if (lin < OUT_W) {
        int j = lin;
        wse[0][j] = x1 + (j * rw) / OUT_W;
        wse[1][j] = x1 + ((j + 1) * rw + OUT_W - 1) / OUT_W;
    }

    int i = ty;
    int hstart = y1 + (i * rh) / OUT_H;
    int hend   = y1 + ((i + 1) * rh + OUT_H - 1) / OUT_H;  // > hstart always

    // Uniform (SGPR) channel-group base + vector 32-bit element offset.
    const float* pbase = feat + ((size_t)b * N_C + c0 + tz * 8) * PLANE;
    int off = hstart * FW + 2 * tx;

    float2 m[8];
    #pragma unroll
    for (int cl = 0; cl < 8; ++cl) { m[cl].x = -INFINITY; m[cl].y = -INFINITY; }

    for (int h = hstart; h < hend; ++h, off += FW) {
        #pragma unroll
        for (int cl = 0; cl < 8; ++cl) {
            float2 v = *(const float2*)&pbase[cl * PLANE + off];
            m[cl].x = fmaxf(m[cl].x, v.x);
            m[cl].y = fmaxf(m[cl].y, v.y);
        }
    }

    #pragma unroll
    for (int cl = 0; cl < 8; ++cl)
        *(float2*)&rowmax[tz * 8 + cl][i][2 * tx] = m[cl];  // b64, 2-way = free

    __syncthreads();

    // ---- Phase B: 196 threads, one (i,j) decode amortized over 4 channels ----
    if (lin < 196) {
        int g   = lin / 49;        // channel group 0..3
        int pos = lin - g * 49;    // 0..48
        int oi  = pos / OUT_W;
        int j   = pos - oi * OUT_W;
        int wstart = wse[0][j];
        int wend   = wse[1][j];    // > wstart always
        float* obase = out + ((size_t)r * N_C + c0) * (OUT_H * OUT_W);
        #pragma unroll
        for (int q = 0; q < 4; ++q) {
            int cl = g * 4 + q;
            float mm = -INFINITY;
            for (int ww = wstart; ww < wend; ++ww)
                mm = fmaxf(mm, rowmax[cl][oi][ww]);
            obase[cl * (OUT_H * OUT_W) + pos] = mm;  // 49-float coalesced runs
        }
    }
}

extern "C" void kernel_launch(void* const* d_in, const int* in_sizes, int n_in,
                              void* d_out, int out_size, void* d_ws, size_t ws_size,
                              hipStream_t stream) {
    const float* feat = (const float*)d_in[0];
    const float* rois = (const float*)d_in[1];
    float* out = (float*)d_out;

    dim3 block(19, OUT_H, 2);        // 19*7*2 = 266 threads (5 waves)
    int  grid = NUM_ROIS * CHUNKS;   // 4096 blocks
    roi_pool_kernel<<<grid, block, 0, stream>>>(feat, rois, out);
}